// Round 6
// baseline (272.214 us; speedup 1.0000x reference)
//
#include <hip/hip_runtime.h>

#define BATCH 128
#define NPTS  4096
#define EPT   8                    // cells per thread
#define WREG  (64 * EPT)           // 512-cell compute region per wave
#define HALOC 104                  // left margin, >= 99 steps of contamination
#define OWN   152                  // owned cells per wave — DECOUPLED from WREG:
                                   // oversubscribed segments buy occupancy
                                   // (3456 waves = 3.375/SIMD) with redundant compute
#define SEGS  27                   // ceil(4096 / 152)
#define TPB   64                   // one independent wave per block

typedef float v4f __attribute__((ext_vector_type(4)));  // clang vector: valid for
                                                        // __builtin_nontemporal_store

// Halved-coefficient flux: g(u) = 0.5*f(u), ah(u) = 0.5*|f'(u)|
// f  = 1.5u + 0.75b u^2 + (-0.5-2b) u^3 + 1.5b u^4 - 0.25b u^6,  b = beta/12
// f' = 1.5 + 1.5b u - (1.5+6b) u^2 + 6b u^3 - 1.5b u^5
__device__ __forceinline__ void flux_eval(float u, float& g, float& ah) {
    constexpr float b  = 0.1f / 12.0f;
    constexpr float c6 = 0.5f * (-0.25f * b);
    constexpr float c4 = 0.5f * ( 1.5f  * b);
    constexpr float c3 = 0.5f * (-0.5f - 2.0f * b);
    constexpr float c2 = 0.5f * ( 0.75f * b);
    constexpr float c1 = 0.5f * ( 1.5f);
    constexpr float d5 = 0.5f * (-1.5f * b);
    constexpr float d3 = 0.5f * ( 6.0f * b);
    constexpr float d2 = 0.5f * (-(1.5f + 6.0f * b));
    constexpr float d1 = 0.5f * ( 1.5f * b);
    constexpr float d0 = 0.5f * ( 1.5f);

    float t = c6 * u;            // c5 == 0
    t = fmaf(t, u, c4);
    t = fmaf(t, u, c3);
    t = fmaf(t, u, c2);
    t = fmaf(t, u, c1);
    g = u * t;

    float e = d5 * u;            // d4 == 0
    e = fmaf(e, u, d3);
    e = fmaf(e, u, d2);
    e = fmaf(e, u, d1);
    e = fmaf(e, u, d0);
    ah = fabsf(e);
}

// One local-Lax-Friedrichs step: dst = step(src), distinct register sets
// (rotation kept from R5 — neutral but harmless; stores drain in background).
__device__ __forceinline__ void pde_step(float (&dst)[EPT], const float (&src)[EPT],
                                         const bool bcL, const bool bcR) {
    const float vl = __shfl_up(src[EPT - 1], 1, 64);
    const float vr = __shfl_down(src[0], 1, 64);

    float vv[EPT + 2];
    vv[0] = vl;
#pragma unroll
    for (int i = 0; i < EPT; ++i) vv[i + 1] = src[i];
    vv[EPT + 1] = vr;

    float g[EPT + 2], a[EPT + 2];
#pragma unroll
    for (int i = 0; i < EPT + 2; ++i) flux_eval(vv[i], g[i], a[i]);

    float fh[EPT + 1];
#pragma unroll
    for (int m = 0; m < EPT + 1; ++m)
        fh[m] = g[m] + g[m + 1] - fmaxf(a[m], a[m + 1]) * (vv[m + 1] - vv[m]);

#pragma unroll
    for (int i = 0; i < EPT; ++i)                  // r = DT/DX = 0.5 exactly
        dst[i] = fmaf(-0.5f, fh[i + 1] - fh[i], src[i]);

    if (bcL) dst[0] = dst[1];                      // u_new[0]   = u_new[1]
    if (bcR) dst[EPT - 1] = dst[EPT - 2];          // u_new[N-1] = u_new[N-2]
}

__device__ __forceinline__ void st8(float* p, const float (&u)[EPT]) {
    v4f lo = {u[0], u[1], u[2], u[3]};
    v4f hi = {u[4], u[5], u[6], u[7]};
    __builtin_nontemporal_store(lo, (v4f*)p);
    __builtin_nontemporal_store(hi, (v4f*)(p + 4));
}

__global__ __launch_bounds__(TPB) void pde_wave_occ(
        const float* __restrict__ init,
        const int*   __restrict__ stepnum_p,
        float*       __restrict__ out) {
    const int wid  = blockIdx.x;
    const int lane = threadIdx.x;
    const int row  = wid / SEGS;
    const int seg  = wid - row * SEGS;

    const int ownlo = seg * OWN;                       // 0, 152, ..., 3952
    // Region [base, base+512): interior margins are >=104 (left) / >=256 (right)
    // around the owned 152 cells — both exceed the 99-step contamination depth.
    // Edge segments clamp to the domain, where the BC (not halo) protects validity.
    const int base  = min(max(ownlo - HALOC, 0), NPTS - WREG);
    const int c0    = base + lane * EPT;               // 32B-aligned
    const bool ownstore = (c0 >= ownlo) && (c0 < ownlo + OWN) && (c0 < NPTS);
    const bool bcL = (seg == 0) && (lane == 0);        // owns cell 0
    const bool bcR = (seg == SEGS - 1) && (lane == 63);// owns cell N-1
    const int stepnum = *stepnum_p;

    const float* ip = init + (size_t)row * NPTS + c0;
    const v4f A  = *(const v4f*)ip;
    const v4f Bv = *(const v4f*)(ip + 4);
    float v[EPT] = {A.x, A.y, A.z, A.w, Bv.x, Bv.y, Bv.z, Bv.w};
    float w[EPT], x[EPT], y[EPT];                      // rotation sets (written first)

    const size_t Z = (size_t)BATCH * NPTS;
    float* op = out + (size_t)row * NPTS + c0;

    if (ownstore) {                                    // out[step=0] = init verbatim
        __builtin_nontemporal_store(A,  (v4f*)op);
        __builtin_nontemporal_store(Bv, (v4f*)(op + 4));
    }
    op += Z;                                           // points at step s=1 slot

    int s = 1;
    for (; s + 3 < stepnum; s += 4) {
        pde_step(w, v, bcL, bcR); if (ownstore) st8(op,         w);
        pde_step(x, w, bcL, bcR); if (ownstore) st8(op + Z,     x);
        pde_step(y, x, bcL, bcR); if (ownstore) st8(op + 2 * Z, y);
        pde_step(v, y, bcL, bcR); if (ownstore) st8(op + 3 * Z, v);
        op += 4 * Z;
    }
    // tail (stepnum=100 -> 99 steps -> 3 remaining)
    if (s < stepnum) {
        pde_step(w, v, bcL, bcR); if (ownstore) st8(op, w); op += Z; ++s;
        if (s < stepnum) {
            pde_step(x, w, bcL, bcR); if (ownstore) st8(op, x); op += Z; ++s;
            if (s < stepnum) {
                pde_step(y, x, bcL, bcR); if (ownstore) st8(op, y);
            }
        }
    }
}

extern "C" void kernel_launch(void* const* d_in, const int* in_sizes, int n_in,
                              void* d_out, int out_size, void* d_ws, size_t ws_size,
                              hipStream_t stream) {
    const float* init  = (const float*)d_in[0];
    const int*   steps = (const int*)d_in[1];
    float*       out   = (float*)d_out;
    pde_wave_occ<<<BATCH * SEGS, TPB, 0, stream>>>(init, steps, out);
}

// Round 7
// 226.629 us; speedup vs baseline: 1.2011x; 1.2011x over previous
//
#include <hip/hip_runtime.h>

#define BATCH 128
#define NPTS  4096
#define HALF  2048
#define TPB   576                 // 9 waves
#define EPT   4
#define CWID  (TPB * EPT)         // 2304-cell compute region per block
#define HALO  (CWID - HALF)       // 256 >= 99 steps of contamination + margin
#define KPL   8                   // output planes staged in LDS between flushes

typedef float v4f __attribute__((ext_vector_type(4)));

// Halved-coefficient flux: g(u) = 0.5*f(u), ah(u) = 0.5*|f'(u)|
// f  = 1.5u + 0.75b u^2 + (-0.5-2b) u^3 + 1.5b u^4 - 0.25b u^6,  b = beta/12
// f' = 1.5 + 1.5b u - (1.5+6b) u^2 + 6b u^3 - 1.5b u^5
__device__ __forceinline__ void flux_eval(float u, float& g, float& ah) {
    constexpr float b  = 0.1f / 12.0f;
    constexpr float c6 = 0.5f * (-0.25f * b);
    constexpr float c4 = 0.5f * ( 1.5f  * b);
    constexpr float c3 = 0.5f * (-0.5f - 2.0f * b);
    constexpr float c2 = 0.5f * ( 0.75f * b);
    constexpr float c1 = 0.5f * ( 1.5f);
    constexpr float d5 = 0.5f * (-1.5f * b);
    constexpr float d3 = 0.5f * ( 6.0f * b);
    constexpr float d2 = 0.5f * (-(1.5f + 6.0f * b));
    constexpr float d1 = 0.5f * ( 1.5f * b);
    constexpr float d0 = 0.5f * ( 1.5f);

    float t = c6 * u;            // c5 == 0
    t = fmaf(t, u, c4);
    t = fmaf(t, u, c3);
    t = fmaf(t, u, c2);
    t = fmaf(t, u, c1);
    g = u * t;

    float e = d5 * u;            // d4 == 0
    e = fmaf(e, u, d3);
    e = fmaf(e, u, d2);
    e = fmaf(e, u, d1);
    e = fmaf(e, u, d0);
    ah = fabsf(e);
}

__global__ __launch_bounds__(TPB) void pde_lds_burst(
        const float* __restrict__ init,
        const int*   __restrict__ stepnum_p,
        float*       __restrict__ out) {
    // Staged output: KPL planes of the block's 2048 owned cells (64 KB), flushed
    // every KPL steps as dense sequential sweeps — store issue decoupled from
    // the compute loop, mimicking the 6.6 TB/s fill kernel's access pattern.
    __shared__ __align__(16) float planes[KPL][HALF];
    __shared__ __align__(8)  float2 edge[2][TPB];

    const int blk  = blockIdx.x;
    const int row  = blk >> 1;
    const int half = blk & 1;
    const int tid  = threadIdx.x;
    const int base = half ? (NPTS - CWID) : 0;          // 1792 or 0
    const int g0   = base + (tid << 2);                 // first cell this thread computes
    const int stepnum = *stepnum_p;

    // owned (uncontaminated) cells; wave-uniform masks:
    // half==0: tid<512 (cells 0..2047); half==1: tid>=64 (cells 2048..4095)
    const bool ownstore = half ? (tid >= (HALO >> 2)) : (tid < (HALF >> 2));
    const int  ownidx   = half ? (g0 - HALF) : g0;      // 0..2047 when ownstore
    const bool rowL = (half == 0) && (tid == 0);
    const bool rowR = (half == 1) && (tid == TPB - 1);
    const int  tl = (tid == 0) ? 0 : tid - 1;           // clamped: garbage feeds only
    const int  tr = (tid == TPB - 1) ? tid : tid + 1;   // contaminated cells

    const float4 v4 = *(const float4*)(init + (size_t)row * NPTS + g0);
    float v0 = v4.x, v1 = v4.y, v2 = v4.z, v3 = v4.w;

    if (ownstore)   // out[step=0] = init (reference applies no boundary copy at s=0)
        *(float4*)(out + (size_t)row * NPTS + g0) = v4;

    const size_t Z = (size_t)BATCH * NPTS;
    const int ownbase = half ? HALF : 0;

    int buf = 0;
    int s = 1;
    while (s < stepnum) {
        const int K = min(KPL, stepnum - s);
        for (int k = 0; k < K; ++k) {
            edge[buf][tid] = make_float2(v0, v3);
            // LDS-visibility-only barrier: never drain vmcnt — flush stores of the
            // previous chunk keep retiring in the background.
            asm volatile("s_waitcnt lgkmcnt(0)\n\ts_barrier" ::: "memory");
            const float vl = edge[buf][tl].y;
            const float vr = edge[buf][tr].x;
            buf ^= 1;

            float g[6], a[6];
            flux_eval(vl, g[0], a[0]);
            flux_eval(v0, g[1], a[1]);
            flux_eval(v1, g[2], a[2]);
            flux_eval(v2, g[3], a[3]);
            flux_eval(v3, g[4], a[4]);
            flux_eval(vr, g[5], a[5]);

            const float vv[6] = { vl, v0, v1, v2, v3, vr };
            float fh[5];
#pragma unroll
            for (int m = 0; m < 5; ++m)
                fh[m] = g[m] + g[m + 1] - fmaxf(a[m], a[m + 1]) * (vv[m + 1] - vv[m]);

            float u0 = fmaf(-0.5f, fh[1] - fh[0], v0);   // r = DT/DX = 0.5 exactly
            float u1 = fmaf(-0.5f, fh[2] - fh[1], v1);
            float u2 = fmaf(-0.5f, fh[3] - fh[2], v2);
            float u3 = fmaf(-0.5f, fh[4] - fh[3], v3);
            if (rowL) u0 = u1;                            // u_new[0]   = u_new[1]
            if (rowR) u3 = u2;                            // u_new[N-1] = u_new[N-2]
            v0 = u0; v1 = u1; v2 = u2; v3 = u3;

            if (ownstore)                                 // mirror owned cells to LDS
                *(v4f*)&planes[k][ownidx] = (v4f){v0, v1, v2, v3};
        }

        // all plane writes visible before cooperative flush (lgkm-only)
        asm volatile("s_waitcnt lgkmcnt(0)\n\ts_barrier" ::: "memory");

        if (tid < (HALF >> 2)) {                          // 512 threads, 8 waves
            float* dst = out + (size_t)s * Z + (size_t)row * NPTS + ownbase + (tid << 2);
#pragma unroll
            for (int p = 0; p < KPL; ++p) {
                if (p < K) {
                    const v4f t = *(const v4f*)&planes[p][tid << 2];
                    *(v4f*)(dst + (size_t)p * Z) = t;     // dense 1KB/instr, sequential
                }
            }
        }

        // protect planes from next chunk's overwrite until all flush reads done
        asm volatile("s_waitcnt lgkmcnt(0)\n\ts_barrier" ::: "memory");
        s += K;
    }
}

extern "C" void kernel_launch(void* const* d_in, const int* in_sizes, int n_in,
                              void* d_out, int out_size, void* d_ws, size_t ws_size,
                              hipStream_t stream) {
    const float* init  = (const float*)d_in[0];
    const int*   steps = (const int*)d_in[1];
    float*       out   = (float*)d_out;
    pde_lds_burst<<<BATCH * 2, TPB, 0, stream>>>(init, steps, out);
}